// Round 4
// baseline (11271.607 us; speedup 1.0000x reference)
//
#include <hip/hip_runtime.h>
#include <math.h>

#define NSLOTS 32
#define DIM    1024
#define NTOK   2048
#define NROWS  32768

#define MOM      0.95f
#define OMM      0.05f
#define MOM2     0.9025f   // 0.95^2
#define MOMOMM2  0.095f    // 2*0.95*0.05
#define OMM2     0.0025f   // 0.05^2
#define INV_TEMP (1.0f/0.35f)
#define COS_EPS  1e-8f
#define NORM_EPS 1e-12f

__device__ __forceinline__ float reduce_all(float v) {
    v += __shfl_xor(v, 32, 64);
    v += __shfl_xor(v, 16, 64);
    v += __shfl_xor(v, 8, 64);
    v += __shfl_xor(v, 4, 64);
    v += __shfl_xor(v, 2, 64);
    v += __shfl_xor(v, 1, 64);
    return v;
}

// 8-value halving butterfly over 64 lanes: returns full-wave sum of v[(lane>>3)&7].
__device__ __forceinline__ float reduce8(const float v[8], int lane) {
    const bool b5 = (lane & 32) != 0;
    const bool b4 = (lane & 16) != 0;
    const bool b3 = (lane & 8) != 0;
    float t[4];
#pragma unroll
    for (int k = 0; k < 4; ++k) {
        float send = b5 ? v[k] : v[k + 4];
        float recv = __shfl_xor(send, 32, 64);
        t[k] = (b5 ? v[k + 4] : v[k]) + recv;
    }
    float u[2];
#pragma unroll
    for (int k = 0; k < 2; ++k) {
        float send = b4 ? t[k] : t[k + 2];
        float recv = __shfl_xor(send, 16, 64);
        u[k] = (b4 ? t[k + 2] : t[k]) + recv;
    }
    float send = b3 ? u[0] : u[1];
    float recv = __shfl_xor(send, 8, 64);
    float r = (b3 ? u[1] : u[0]) + recv;
    r += __shfl_xor(r, 4, 64);
    r += __shfl_xor(r, 2, 64);
    r += __shfl_xor(r, 1, 64);
    return r;
}

// 4-value variant; result for r = (lane>>4)&3.
__device__ __forceinline__ float reduce4(const float v[4], int lane) {
    const bool b5 = (lane & 32) != 0;
    const bool b4 = (lane & 16) != 0;
    float t[2];
#pragma unroll
    for (int k = 0; k < 2; ++k) {
        float send = b5 ? v[k] : v[k + 2];
        float recv = __shfl_xor(send, 32, 64);
        t[k] = (b5 ? v[k + 2] : v[k]) + recv;
    }
    float send = b4 ? t[0] : t[1];
    float recv = __shfl_xor(send, 16, 64);
    float r = (b4 ? t[1] : t[0]) + recv;
    r += __shfl_xor(r, 8, 64);
    r += __shfl_xor(r, 4, 64);
    r += __shfl_xor(r, 2, 64);
    r += __shfl_xor(r, 1, 64);
    return r;
}

// ---- DPP wave-max (VALU pipe, no LDS): max of all 64 lanes, broadcast.
// Canonical GCN sequence: row_shr 1/2/4/8 accumulates toward lane 15 of each
// 16-lane row; row_bcast15 (rows 1,3) then row_bcast31 (rows 2,3) fold rows;
// lane 63 holds the global max. (Round-3 bug: used row_shl, which folds
// toward lane 0 and makes the bcasts propagate garbage.)
template<int CTRL, int ROW_MASK>
__device__ __forceinline__ float dpp_mov(float v) {
    int i = __builtin_bit_cast(int, v);
    int r = __builtin_amdgcn_update_dpp(i, i, CTRL, ROW_MASK, 0xF, false);
    return __builtin_bit_cast(float, r);
}

__device__ __forceinline__ float wave_max_dpp(float v) {
    v = fmaxf(v, dpp_mov<0x111, 0xF>(v));  // row_shr:1
    v = fmaxf(v, dpp_mov<0x112, 0xF>(v));  // row_shr:2
    v = fmaxf(v, dpp_mov<0x114, 0xF>(v));  // row_shr:4
    v = fmaxf(v, dpp_mov<0x118, 0xF>(v));  // row_shr:8  -> lane15 of row = row max
    v = fmaxf(v, dpp_mov<0x142, 0xA>(v));  // row_bcast15 -> rows 1,3
    v = fmaxf(v, dpp_mov<0x143, 0xC>(v));  // row_bcast31 -> rows 2,3; lane63 = global
    int m = __builtin_amdgcn_readlane(__builtin_bit_cast(int, v), 63);
    return __builtin_bit_cast(float, m);
}

// ---------------------------------------------------------------------------
// Kernel 1: G = wb . wb^T  (fp32, upper-triangle tiles only; 64x64 tile/block)
// G lives in the FRONT OF d_out (16 MB scratch) — retrieve overwrites it last.
// ---------------------------------------------------------------------------
__global__ __launch_bounds__(256) void gram_kernel(const float* __restrict__ W,
                                                   float* __restrict__ G) {
    const int bi = blockIdx.x & 31;
    const int bj = blockIdx.x >> 5;
    if (bj < bi) return;                 // scan only reads G[t][t'>=t]
    __shared__ float As[16][68];         // [k][row], stride 68 -> conflict-free
    __shared__ float Bs[16][68];
    const int tid = threadIdx.x;
    const int lr = tid >> 2;             // 0..63
    const int kc = (tid & 3) * 4;        // 0,4,8,12
    const int ti = tid & 15, tj = tid >> 4;
    const int i0 = bi * 64, j0 = bj * 64;
    float acc[4][4] = {};
#pragma unroll 1
    for (int k0 = 0; k0 < DIM; k0 += 16) {
        float4 av = *(const float4*)&W[(size_t)(i0 + lr) * DIM + k0 + kc];
        float4 bv = *(const float4*)&W[(size_t)(j0 + lr) * DIM + k0 + kc];
        __syncthreads();
        As[kc + 0][lr] = av.x; As[kc + 1][lr] = av.y;
        As[kc + 2][lr] = av.z; As[kc + 3][lr] = av.w;
        Bs[kc + 0][lr] = bv.x; Bs[kc + 1][lr] = bv.y;
        Bs[kc + 2][lr] = bv.z; Bs[kc + 3][lr] = bv.w;
        __syncthreads();
#pragma unroll
        for (int kk = 0; kk < 16; ++kk) {
            float4 a = *(const float4*)&As[kk][4 * ti];
            float4 b = *(const float4*)&Bs[kk][4 * tj];
            acc[0][0] = fmaf(a.x, b.x, acc[0][0]);
            acc[0][1] = fmaf(a.x, b.y, acc[0][1]);
            acc[0][2] = fmaf(a.x, b.z, acc[0][2]);
            acc[0][3] = fmaf(a.x, b.w, acc[0][3]);
            acc[1][0] = fmaf(a.y, b.x, acc[1][0]);
            acc[1][1] = fmaf(a.y, b.y, acc[1][1]);
            acc[1][2] = fmaf(a.y, b.z, acc[1][2]);
            acc[1][3] = fmaf(a.y, b.w, acc[1][3]);
            acc[2][0] = fmaf(a.z, b.x, acc[2][0]);
            acc[2][1] = fmaf(a.z, b.y, acc[2][1]);
            acc[2][2] = fmaf(a.z, b.z, acc[2][2]);
            acc[2][3] = fmaf(a.z, b.w, acc[2][3]);
            acc[3][0] = fmaf(a.w, b.x, acc[3][0]);
            acc[3][1] = fmaf(a.w, b.y, acc[3][1]);
            acc[3][2] = fmaf(a.w, b.z, acc[3][2]);
            acc[3][3] = fmaf(a.w, b.w, acc[3][3]);
        }
    }
#pragma unroll
    for (int r = 0; r < 4; ++r) {
        float4 o = {acc[r][0], acc[r][1], acc[r][2], acc[r][3]};
        *(float4*)&G[(size_t)(i0 + 4 * ti + r) * NTOK + j0 + 4 * tj] = o;
    }
}

// ---------------------------------------------------------------------------
// Kernel 1b: D[s][t'] = dot(init_slot_s, tok_t')  (zeros for given inputs,
// but general). 64 blocks x 4 waves; each wave 8 tokens.
// ---------------------------------------------------------------------------
__global__ __launch_bounds__(256) void dinit_kernel(
    const float* __restrict__ slots, const float* __restrict__ wb,
    float* __restrict__ D) {
    const int w = threadIdx.x >> 6, j = threadIdx.x & 63;
    const int gw = blockIdx.x * 4 + w;   // 0..255
#pragma unroll 1
    for (int rep = 0; rep < 8; ++rep) {
        const int tp = gw + 256 * rep;
        float tv[16];
#pragma unroll
        for (int q = 0; q < 4; ++q) {
            float4 v = *(const float4*)&wb[(size_t)tp * DIM + 256 * q + 4 * j];
            tv[4*q+0] = v.x; tv[4*q+1] = v.y; tv[4*q+2] = v.z; tv[4*q+3] = v.w;
        }
#pragma unroll 1
        for (int g = 0; g < 4; ++g) {
            float vv[8];
#pragma unroll
            for (int i = 0; i < 8; ++i) {
                const int s = 8 * g + i;
                float a = 0.0f;
#pragma unroll
                for (int q = 0; q < 4; ++q) {
                    float4 v = *(const float4*)&slots[(size_t)s * DIM + 256 * q + 4 * j];
                    a = fmaf(v.x, tv[4*q+0], a);
                    a = fmaf(v.y, tv[4*q+1], a);
                    a = fmaf(v.z, tv[4*q+2], a);
                    a = fmaf(v.w, tv[4*q+3], a);
                }
                vv[i] = a;
            }
            float d = reduce8(vv, j);
            if ((j & 7) == 0) D[(size_t)(8 * g + (j >> 3)) * NTOK + tp] = d;
        }
    }
}

// ---------------------------------------------------------------------------
// Kernel 2: the sequential routing scan — SINGLE WAVE, no barriers, no LDS.
// Maintains D[s][t'] = dot(current slot_s, tok_t') eagerly in global (L2).
// Serial chain touches registers only: sims column software-pipelined with
// in-register patch of the chosen row.
// ---------------------------------------------------------------------------
__global__ __launch_bounds__(64, 1) void scan_kernel(
    const float* __restrict__ G, float* __restrict__ D,
    const float* __restrict__ usage_in, const float* __restrict__ slots_in,
    int* __restrict__ pack, float* __restrict__ ns_out)
{
    const int lane = threadIdx.x;

    // initial slot squared-norms -> lane s holds slot s state
    float ssd = 0.0f, invd = 0.0f;
#pragma unroll 1
    for (int s = 0; s < NSLOTS; ++s) {
        float p = 0.0f;
#pragma unroll
        for (int k = 0; k < 16; ++k) {
            float v = slots_in[s * DIM + 64 * k + lane];
            p = fmaf(v, v, p);
        }
        p = reduce_all(p);
        if (lane == s) { ssd = p; invd = 1.0f / fmaxf(sqrtf(p), COS_EPS); }
    }
    float uval = (lane < NSLOTS) ? usage_in[lane] : 1.0f;
    unsigned emptyMask = (unsigned)__ballot(uval == 0.0f);

    // pipeline prime: dcur = D[:,0], dnext = D[:,1]; G diag pairs for t=0,1
    float dcur  = (lane < NSLOTS) ? D[lane * NTOK + 0] : 0.0f;
    float dnext = (lane < NSLOTS) ? D[lane * NTOK + 1] : 0.0f;
    float g_tt_c = G[0];
    float g_t1_c = G[1];
    float g_tt_n = G[1 * NTOK + 1];
    float g_t1_n = G[1 * NTOK + 2];

#pragma unroll 1
    for (int t = 0; t < NTOK; ++t) {
        int idx;
        if (emptyMask) {                        // uniform: first empty slot
            idx = __ffs(emptyMask) - 1;
            emptyMask &= (emptyMask - 1);
        } else {
            const float invnt = 1.0f / fmaxf(sqrtf(g_tt_c), COS_EPS);
            const float sim = (lane < NSLOTS) ? dcur * invd * invnt : -INFINITY;
            const float vmax = wave_max_dpp(sim);
            const unsigned long long bm = __ballot(sim == vmax);
            idx = __builtin_ctzll(bm);          // first max = lowest index
        }
        if (lane == idx) {
            // ||.95 a + .05 b||^2 = .9025||a||^2 + .095 a.b + .0025||b||^2
            ssd = MOM2 * ssd + MOMOMM2 * dcur + OMM2 * g_tt_c;
            invd = 1.0f / fmaxf(sqrtf(ssd), COS_EPS);
        }
        if (lane == 0) pack[t] = idx;
        // advance sims column: patch chosen row in-register (no memory dep)
        {
            const float nd = MOM * dnext + OMM * g_t1_c;
            dcur = (lane == idx) ? nd : dnext;
        }
        // bulk RMW of chosen slot's future dots (coalesced dwords)
        {
            const float* Grow = G + (size_t)t * NTOK;
            float* Drow = D + (size_t)idx * NTOK;
            const int A = (t + 1) & ~63;
#pragma unroll 1
            for (int base = A; base < NTOK; base += 64) {
                const int tp = base + lane;
                if (tp > t) Drow[tp] = fmaf(MOM, Drow[tp], OMM * Grow[tp]);
            }
        }
        // drain stores so next column prefetch can't read stale D
        asm volatile("s_waitcnt vmcnt(0)" ::: "memory");
        // prefetch: D column t+2 (1 step ahead), G diag pair t+2 (2 ahead)
        float g_tt_m = g_tt_n, g_t1_m = g_t1_n;
        if (t + 2 < NTOK) {
            dnext = (lane < NSLOTS) ? D[lane * NTOK + (t + 2)] : 0.0f;
            g_tt_m = G[(size_t)(t + 2) * NTOK + (t + 2)];
            g_t1_m = (t + 3 < NTOK) ? G[(size_t)(t + 2) * NTOK + (t + 3)] : 0.0f;
        }
        g_tt_c = g_tt_n; g_t1_c = g_t1_n;
        g_tt_n = g_tt_m; g_t1_n = g_t1_m;
    }
    if (lane < NSLOTS) ns_out[lane] = sqrtf(ssd);
}

// ---------------------------------------------------------------------------
// Kernel 3: reconstruct final slots from the routing record, write normalized
// slots. slot_s = 0.95^m_s * init_s + sum_u 0.05 * 0.95^(m_s - a_u) * tok_u
// ---------------------------------------------------------------------------
__global__ __launch_bounds__(256) void recon_kernel(
    const float* __restrict__ slots_in, const float* __restrict__ wb,
    const int* __restrict__ pack, const float* __restrict__ ns_in,
    float* __restrict__ sn_out)
{
    const int s = blockIdx.x;
    const int tid = threadIdx.x;
    const float LOG2_095 = -0.07400058144377693f;  // log2(0.95)

    int cnt = 0;
#pragma unroll 1
    for (int u = 0; u < NTOK; ++u) cnt += (pack[u] == s) ? 1 : 0;

    float4 acc;
    {
        const float c0 = exp2f((float)cnt * LOG2_095);
        const float4 s0 = *(const float4*)&slots_in[s * DIM + 4 * tid];
        acc.x = c0 * s0.x; acc.y = c0 * s0.y; acc.z = c0 * s0.z; acc.w = c0 * s0.w;
    }
    int seen = 0;
#pragma unroll 1
    for (int u = 0; u < NTOK; ++u) {
        if (pack[u] == s) {
            ++seen;
            const float coef = OMM * exp2f((float)(cnt - seen) * LOG2_095);
            const float4 tv = *(const float4*)&wb[(size_t)u * DIM + 4 * tid];
            acc.x = fmaf(coef, tv.x, acc.x);
            acc.y = fmaf(coef, tv.y, acc.y);
            acc.z = fmaf(coef, tv.z, acc.z);
            acc.w = fmaf(coef, tv.w, acc.w);
        }
    }
    const float inv = 1.0f / fmaxf(ns_in[s], NORM_EPS);
    float4 o = {acc.x * inv, acc.y * inv, acc.z * inv, acc.w * inv};
    *(float4*)&sn_out[s * DIM + 4 * tid] = o;
}

// ---------------------------------------------------------------------------
// Retrieve (unchanged from round 1 — passed): 1024 blocks x 512 threads,
// wave per 4 rows, normalized slots staged through LDS in 8-slot passes.
// Overwrites ALL of d_out, including the G/D scratch at its front.
// ---------------------------------------------------------------------------
__global__ __launch_bounds__(512, 2) void retrieve_kernel(
    const float* __restrict__ x,
    const float* __restrict__ sn_g,
    const float* __restrict__ ns_g,
    float* __restrict__ out)
{
    __shared__ __align__(16) float snL[8 * DIM];          // 32 KB
    __shared__ float nsL[NSLOTS];
    __shared__ __align__(16) float scL[8 * 4 * NSLOTS];   // [wave][row][slot]

    const int tid = threadIdx.x;
    const int w = tid >> 6;
    const int j = tid & 63;

    if (tid < NSLOTS) nsL[tid] = ns_g[tid];

    const int rowbase = (blockIdx.x * 8 + w) * 4;

    float xv[4][16];
#pragma unroll
    for (int r = 0; r < 4; ++r) {
        const float* xr = &x[(long)(rowbase + r) * DIM];
#pragma unroll
        for (int q = 0; q < 4; ++q) {
            float4 v = *(const float4*)&xr[256 * q + 4 * j];
            xv[r][4*q+0] = v.x; xv[r][4*q+1] = v.y;
            xv[r][4*q+2] = v.z; xv[r][4*q+3] = v.w;
        }
    }
    float mul[4];
#pragma unroll
    for (int r = 0; r < 4; ++r) {
        float a = 0.0f;
#pragma unroll
        for (int k = 0; k < 16; ++k) a = fmaf(xv[r][k], xv[r][k], a);
        a = reduce_all(a);
        mul[r] = (1.0f / fmaxf(sqrtf(a), NORM_EPS)) * INV_TEMP;
    }

#pragma unroll 1
    for (int h = 0; h < 4; ++h) {
        if (h) __syncthreads();
        for (int i = tid; i < 8 * DIM / 4; i += 512)
            *(float4*)&snL[4 * i] = *(const float4*)&sn_g[h * 8 * DIM + 4 * i];
        __syncthreads();
#pragma unroll 1
        for (int si = 0; si < 8; ++si) {
            const int s = 8 * h + si;
            float snv[16];
#pragma unroll
            for (int q = 0; q < 4; ++q) {
                float4 v = *(const float4*)&snL[si * DIM + 256 * q + 4 * j];
                snv[4*q+0]=v.x; snv[4*q+1]=v.y; snv[4*q+2]=v.z; snv[4*q+3]=v.w;
            }
            float p[4];
#pragma unroll
            for (int r = 0; r < 4; ++r) {
                float a = 0.0f;
#pragma unroll
                for (int k = 0; k < 16; ++k) a = fmaf(xv[r][k], snv[k], a);
                p[r] = a;
            }
            float d = reduce4(p, j);
            if ((j & 15) == 0) scL[w * 128 + (j >> 4) * 32 + s] = d;
        }
    }

    {
        const int r = j & 3;
        const float mulr = (r == 0) ? mul[0] : (r == 1) ? mul[1]
                         : (r == 2) ? mul[2] : mul[3];
        float sc[32];
#pragma unroll
        for (int s4 = 0; s4 < 8; ++s4) {
            float4 v = *(const float4*)&scL[w * 128 + r * 32 + 4 * s4];
            sc[4*s4+0]=v.x; sc[4*s4+1]=v.y; sc[4*s4+2]=v.z; sc[4*s4+3]=v.w;
        }
        float m = -INFINITY;
#pragma unroll
        for (int s = 0; s < 32; ++s) { sc[s] *= mulr; m = fmaxf(m, sc[s]); }
        float sum = 0.0f;
#pragma unroll
        for (int s = 0; s < 32; ++s) { sc[s] = expf(sc[s] - m); sum += sc[s]; }
        const float isum = 1.0f / sum;
        if (j < 4) {
#pragma unroll
            for (int s4 = 0; s4 < 8; ++s4) {
                float4 o;
                o.x = sc[4*s4+0] * isum * nsL[4*s4+0];
                o.y = sc[4*s4+1] * isum * nsL[4*s4+1];
                o.z = sc[4*s4+2] * isum * nsL[4*s4+2];
                o.w = sc[4*s4+3] * isum * nsL[4*s4+3];
                *(float4*)&scL[w * 128 + j * 32 + 4 * s4] = o;
            }
        }
    }

    float acc[4][16];
#pragma unroll
    for (int r = 0; r < 4; ++r)
#pragma unroll
        for (int k = 0; k < 16; ++k) acc[r][k] = 0.0f;

#pragma unroll 1
    for (int h = 3; h >= 0; --h) {
        if (h != 3) {
            __syncthreads();
            for (int i = tid; i < 8 * DIM / 4; i += 512)
                *(float4*)&snL[4 * i] = *(const float4*)&sn_g[h * 8 * DIM + 4 * i];
            __syncthreads();
        }
#pragma unroll 1
        for (int si = 0; si < 8; ++si) {
            const int s = 8 * h + si;
            float snv[16];
#pragma unroll
            for (int q = 0; q < 4; ++q) {
                float4 v = *(const float4*)&snL[si * DIM + 256 * q + 4 * j];
                snv[4*q+0]=v.x; snv[4*q+1]=v.y; snv[4*q+2]=v.z; snv[4*q+3]=v.w;
            }
#pragma unroll
            for (int r = 0; r < 4; ++r) {
                const float ww = scL[w * 128 + r * 32 + s];
#pragma unroll
                for (int k = 0; k < 16; ++k) acc[r][k] = fmaf(ww, snv[k], acc[r][k]);
            }
        }
    }

#pragma unroll
    for (int r = 0; r < 4; ++r) {
        float* orow = &out[(long)(rowbase + r) * DIM];
#pragma unroll
        for (int q = 0; q < 4; ++q) {
            float4 o;
            o.x = acc[r][4*q+0]; o.y = acc[r][4*q+1];
            o.z = acc[r][4*q+2]; o.w = acc[r][4*q+3];
            *(float4*)&orow[256 * q + 4 * j] = o;
        }
    }
}

extern "C" void kernel_launch(void* const* d_in, const int* in_sizes, int n_in,
                              void* d_out, int out_size, void* d_ws, size_t ws_size,
                              hipStream_t stream) {
    const float* x  = (const float*)d_in[0];   // [4,8192,1024]
    const float* wb = (const float*)d_in[1];   // [2048,1024]
    const float* sl = (const float*)d_in[2];   // [32,1024]
    const float* us = (const float*)d_in[3];   // [32]
    float* out = (float*)d_out;

    // Big scratch lives in the FRONT of d_out (134 MB guaranteed); it is
    // consumed by scan_kernel and then fully overwritten by retrieve_kernel.
    // d_ws holds only the small buffers retrieve/recon must read (~139 KB).
    float* G    = out;                          // 2048*2048  (16 MB)
    float* D    = out + (size_t)NTOK * NTOK;    // 32*2048    (256 KB)
    float* sn   = (float*)d_ws;                 // 32*1024
    float* ns   = sn + NSLOTS * DIM;            // 32
    int*   pack = (int*)(ns + NSLOTS);          // 2048

    gram_kernel    <<<dim3(1024),        dim3(256), 0, stream>>>(wb, G);
    dinit_kernel   <<<dim3(64),          dim3(256), 0, stream>>>(sl, wb, D);
    scan_kernel    <<<dim3(1),           dim3(64),  0, stream>>>(G, D, us, sl, pack, ns);
    recon_kernel   <<<dim3(NSLOTS),      dim3(256), 0, stream>>>(sl, wb, pack, ns, sn);
    retrieve_kernel<<<dim3(NROWS / 32),  dim3(512), 0, stream>>>(x, sn, ns, out);
}